// Round 10
// baseline (1599.412 us; speedup 1.0000x reference)
//
#include <hip/hip_runtime.h>

#define B 4
#define N1 2048
#define N2 8192
#define C1 128
#define C2 64
#define K 15
#define F 128
#define S 16

// ---------------------------------------------------------------------------
// kNN: R9-VERBATIM (validated: absmax 0.03125). 512 threads = 16 queries x
// 32 subchunk lists; strided subscans + 5-round lex-(d,idx) tree merge.
// ---------------------------------------------------------------------------
__global__ __launch_bounds__(512) void knn_kernel(
    const float* __restrict__ xyz1, const float* __restrict__ xyz2,
    unsigned short* __restrict__ nn_idx) {
#pragma clang fp contract(off)
  __shared__ float sx[N1], sy[N1], sz[N1];
  __shared__ float s_cd[16][522];
  __shared__ unsigned short s_ci[16][522];
  const int b = blockIdx.y;
  const int q0 = blockIdx.x * 16;
  const int tid = threadIdx.x;

  const float* p1 = xyz1 + (size_t)b * N1 * 3;
  for (int i = tid; i < N1; i += 512) {
    sx[i] = p1[i * 3 + 0];
    sy[i] = p1[i * 3 + 1];
    sz[i] = p1[i * 3 + 2];
  }
  __syncthreads();

  const int wv = tid >> 6;
  const int lane = tid & 63;
  const int q = lane & 15;
  const int sub = lane >> 4;
  const float* p2 = xyz2 + ((size_t)b * N2 + q0 + q) * 3;
  const float qx = p2[0], qy = p2[1], qz = p2[2];

  float bd[S];
  int bi[S];
#pragma unroll
  for (int j = 0; j < S; ++j) { bd[j] = 3.4e38f; bi[j] = 0x7fffffff; }

  const int i0 = wv * 256 + sub;
  for (int ii = 0; ii < 64; ++ii) {
    const int i = i0 + (ii << 2);
    float dx = qx - sx[i];
    float dy = qy - sy[i];
    float dz = qz - sz[i];
    float d = dx * dx;
    d = d + dy * dy;
    d = d + dz * dz;
    if (d < bd[S - 1]) {
      bd[S - 1] = d;
      bi[S - 1] = i;
#pragma unroll
      for (int j = S - 1; j > 0; --j) {
        if (bd[j] < bd[j - 1]) {
          float td = bd[j]; bd[j] = bd[j - 1]; bd[j - 1] = td;
          int ti = bi[j]; bi[j] = bi[j - 1]; bi[j - 1] = ti;
        }
      }
    }
  }
  {
    const int ls = (wv * 4 + sub) * 16;
#pragma unroll
    for (int j = 0; j < S; ++j) {
      s_cd[q][ls + j] = bd[j];
      s_ci[q][ls + j] = (unsigned short)bi[j];
    }
  }
  __syncthreads();

  for (int L = 32; L >= 4; L >>= 1) {
    const int half = L >> 1;
    const int nact = 16 * half;
    const int valid = tid < nact;
    float od[16];
    int oi[16];
    int q2 = 0, m = 0;
    if (valid) {
      q2 = tid / half;
      m = tid - q2 * half;
      int pa = (2 * m) * 16, ea = pa + 16;
      int pb = ea, eb = pb + 16;
#pragma unroll
      for (int j = 0; j < 16; ++j) {
        const int a_ok = pa < ea, b_ok = pb < eb;
        const int ra = a_ok ? pa : ea - 1;
        const int rb = b_ok ? pb : eb - 1;
        float da = s_cd[q2][ra];
        int ia = (int)s_ci[q2][ra];
        float db = s_cd[q2][rb];
        int ib = (int)s_ci[q2][rb];
        const int ta = a_ok && (!b_ok || da < db || (da == db && ia < ib));
        od[j] = ta ? da : db;
        oi[j] = ta ? ia : ib;
        pa += ta;
        pb += !ta;
      }
    }
    __syncthreads();
    if (valid) {
#pragma unroll
      for (int j = 0; j < 16; ++j) {
        s_cd[q2][m * 16 + j] = od[j];
        s_ci[q2][m * 16 + j] = (unsigned short)oi[j];
      }
    }
    __syncthreads();
  }

  if (tid < 16) {
    const int q2 = tid;
    int pa = 0, ea = 16, pb = 16, eb = 32;
    unsigned short* op = nn_idx + ((size_t)b * N2 + q0 + q2) * S;
#pragma unroll
    for (int j = 0; j < 16; ++j) {
      const int a_ok = pa < ea, b_ok = pb < eb;
      const int ra = a_ok ? pa : ea - 1;
      const int rb = b_ok ? pb : eb - 1;
      float da = s_cd[q2][ra];
      int ia = (int)s_ci[q2][ra];
      float db = s_cd[q2][rb];
      int ib = (int)s_ci[q2][rb];
      const int ta = a_ok && (!b_ok || da < db || (da == db && ia < ib));
      op[j] = (unsigned short)(ta ? ia : ib);
      pa += ta;
      pb += !ta;
    }
  }
}

// ---------------------------------------------------------------------------
// Conv: 512 threads, 32 queries/block. Phase B k-chunked (3 x 5 kernel
// points, wfr[5][8] = 40 regs) so VGPR fits 128 -> 16 waves/CU. Phase C per
// k: stage wf to LDS, (qg, cs, fg) register tile, 32 FMA/c2. Reduction:
// shfl_xor(32) for in-wave cs-pair, one LDS round-trip across wave pairs.
// Accumulation order bitwise identical to R8 (k, c2 ascending).
// No LDS aliasing (R9 lesson).
// ---------------------------------------------------------------------------
__global__ __launch_bounds__(512, 4) void conv_kernel(
    const float* __restrict__ xyz1, const float* __restrict__ feat1,
    const float* __restrict__ xyz2, const float* __restrict__ feat2,
    const float* __restrict__ kp, const float* __restrict__ W,
    const unsigned short* __restrict__ nn_idx, float* __restrict__ out) {
  __shared__ int s_idx[32][S];          //  2 KB
  __shared__ float s_rel[32][S][3];     //  6 KB
  __shared__ float s_w[32][260];        // 33.3 KB
  __shared__ float s_wf[C1][36];        // 18.4 KB
  __shared__ float s_part[4][8][132];   // 16.9 KB
  __shared__ float s_kp[K * 3];

  const int b = blockIdx.y;
  const int q0 = blockIdx.x * 32;
  const int tid = threadIdx.x;

  if (tid < K * 3) s_kp[tid] = kp[tid];
  s_idx[tid >> 4][tid & 15] = (int)nn_idx[((size_t)b * N2 + q0) * S + tid];
  __syncthreads();

  // Phase A0: rel = neigh_xyz - query (one (q,s) per thread)
  {
    int q = tid >> 4, s = tid & 15;
    int i = s_idx[q][s];
    const float* pn = xyz1 + ((size_t)b * N1 + i) * 3;
    const float* pq = xyz2 + ((size_t)b * N2 + q0 + q) * 3;
    s_rel[q][s][0] = pn[0] - pq[0];
    s_rel[q][s][1] = pn[1] - pq[1];
    s_rel[q][s][2] = pn[2] - pq[2];
  }
  __syncthreads();

  // Phase A1: kernel-point weights w[q][s][k]  (32*16*15 = 7680 = 15*512)
  for (int t = tid; t < 32 * S * K; t += 512) {
    int q = t / (S * K);
    int r = t - q * (S * K);
    int s = r / K;
    int k = r - s * K;
    float rx = s_rel[q][s][0] - s_kp[k * 3 + 0];
    float ry = s_rel[q][s][1] - s_kp[k * 3 + 1];
    float rz = s_rel[q][s][2] - s_kp[k * 3 + 2];
    float d = sqrtf(fmaxf(rx * rx + ry * ry + rz * rz, 1e-12f));
    s_w[q][s * 16 + k] = fmaxf(0.0f, 1.0f - d / 0.2f);
  }
  __syncthreads();

  const int q = tid & 31;        // phase-B query
  const int cg = tid >> 5;       // phase-B c-group (c = cg*8 .. +8)
  const int qg = tid >> 7;       // phase-C q-octet (q = qg*8+qi)
  const int cs = (tid >> 5) & 3; // phase-C c-quarter
  const int fg = tid & 31;       // phase-C f-quad (f = fg*4 .. +4)

  float4 acc[8];
#pragma unroll
  for (int qi = 0; qi < 8; ++qi) acc[qi] = make_float4(0.f, 0.f, 0.f, 0.f);

#pragma unroll
  for (int kc = 0; kc < 3; ++kc) {
    // Phase B chunk: wfr[kk][j], k = kc*5 + kk
    float wfr[5][8];
#pragma unroll
    for (int kk = 0; kk < 5; ++kk)
#pragma unroll
      for (int j = 0; j < 8; ++j) wfr[kk][j] = 0.0f;

    for (int s = 0; s < S; ++s) {
      int i = s_idx[q][s];
      const float4* fp =
          (const float4*)(feat1 + ((size_t)b * N1 + i) * C1) + cg * 2;
      float4 n0 = fp[0];
      float4 n1 = fp[1];
      const float4* wr = (const float4*)(&s_w[q][s * 16]);
      float4 w0 = wr[0], w1 = wr[1], w2 = wr[2], w3 = wr[3];
      float wk[16] = {w0.x, w0.y, w0.z, w0.w, w1.x, w1.y, w1.z, w1.w,
                      w2.x, w2.y, w2.z, w2.w, w3.x, w3.y, w3.z, w3.w};
#pragma unroll
      for (int kk = 0; kk < 5; ++kk) {
        float w = wk[kc * 5 + kk];
        wfr[kk][0] += w * n0.x;
        wfr[kk][1] += w * n0.y;
        wfr[kk][2] += w * n0.z;
        wfr[kk][3] += w * n0.w;
        wfr[kk][4] += w * n1.x;
        wfr[kk][5] += w * n1.y;
        wfr[kk][6] += w * n1.z;
        wfr[kk][7] += w * n1.w;
      }
    }

    // Phase C: 5 k-steps of this chunk
#pragma unroll
    for (int kk = 0; kk < 5; ++kk) {
      const int k = kc * 5 + kk;
      __syncthreads();   // prior s_wf consumers done
#pragma unroll
      for (int j = 0; j < 8; ++j) s_wf[cg * 8 + j][q] = wfr[kk][j];
      __syncthreads();

      const float4* Wk4 = (const float4*)(W + (size_t)k * C1 * F) + fg;
#pragma unroll 4
      for (int c2 = 0; c2 < 32; ++c2) {
        int c = cs * 32 + c2;
        float4 wa = *(const float4*)(&s_wf[c][qg * 8 + 0]);
        float4 wb = *(const float4*)(&s_wf[c][qg * 8 + 4]);
        float4 w4 = Wk4[c * 32];
        acc[0].x += wa.x * w4.x; acc[0].y += wa.x * w4.y;
        acc[0].z += wa.x * w4.z; acc[0].w += wa.x * w4.w;
        acc[1].x += wa.y * w4.x; acc[1].y += wa.y * w4.y;
        acc[1].z += wa.y * w4.z; acc[1].w += wa.y * w4.w;
        acc[2].x += wa.z * w4.x; acc[2].y += wa.z * w4.y;
        acc[2].z += wa.z * w4.z; acc[2].w += wa.z * w4.w;
        acc[3].x += wa.w * w4.x; acc[3].y += wa.w * w4.y;
        acc[3].z += wa.w * w4.z; acc[3].w += wa.w * w4.w;
        acc[4].x += wb.x * w4.x; acc[4].y += wb.x * w4.y;
        acc[4].z += wb.x * w4.z; acc[4].w += wb.x * w4.w;
        acc[5].x += wb.y * w4.x; acc[5].y += wb.y * w4.y;
        acc[5].z += wb.y * w4.z; acc[5].w += wb.y * w4.w;
        acc[6].x += wb.z * w4.x; acc[6].y += wb.z * w4.y;
        acc[6].z += wb.z * w4.z; acc[6].w += wb.z * w4.w;
        acc[7].x += wb.w * w4.x; acc[7].y += wb.w * w4.y;
        acc[7].z += wb.w * w4.z; acc[7].w += wb.w * w4.w;
      }
    }
  }

  // Reduce cs-pair within wave (lanes L and L^32 share qg, fg; cs differs)
#pragma unroll
  for (int qi = 0; qi < 8; ++qi) {
    acc[qi].x += __shfl_xor(acc[qi].x, 32, 64);
    acc[qi].y += __shfl_xor(acc[qi].y, 32, 64);
    acc[qi].z += __shfl_xor(acc[qi].z, 32, 64);
    acc[qi].w += __shfl_xor(acc[qi].w, 32, 64);
  }

  // Cross-wave: odd wave (csg=1, c 64..127) writes partials; even wave adds.
  const int wv = tid >> 6;
  const int lane = tid & 63;
  __syncthreads();   // s_wf fully consumed; also orders s_part vs below
  if ((wv & 1) && lane < 32) {
#pragma unroll
    for (int qi = 0; qi < 8; ++qi)
      *(float4*)(&s_part[qg][qi][fg * 4]) = acc[qi];
  }
  __syncthreads();
  if (!(wv & 1) && lane < 32) {
#pragma unroll
    for (int qi = 0; qi < 8; ++qi) {
      float4 p = *(const float4*)(&s_part[qg][qi][fg * 4]);
      float4 v;
      v.x = fmaxf(acc[qi].x + p.x, 0.0f);
      v.y = fmaxf(acc[qi].y + p.y, 0.0f);
      v.z = fmaxf(acc[qi].z + p.z, 0.0f);
      v.w = fmaxf(acc[qi].w + p.w, 0.0f);
      ((float4*)(out + ((size_t)b * N2 + q0 + qg * 8 + qi) * (F + C2)))[fg] = v;
    }
  }

  // Concat skip features2 (32 q x 16 float4 = 512, one per thread)
  {
    int qq = tid >> 4;
    int j = tid & 15;
    float4 v = ((const float4*)(feat2 + ((size_t)b * N2 + q0 + qq) * C2))[j];
    ((float4*)(out + ((size_t)b * N2 + q0 + qq) * (F + C2) + F))[j] = v;
  }
}

extern "C" void kernel_launch(void* const* d_in, const int* in_sizes, int n_in,
                              void* d_out, int out_size, void* d_ws, size_t ws_size,
                              hipStream_t stream) {
  const float* xyz1 = (const float*)d_in[0];
  const float* feat1 = (const float*)d_in[1];
  const float* xyz2 = (const float*)d_in[2];
  const float* feat2 = (const float*)d_in[3];
  const float* kp = (const float*)d_in[4];
  const float* Wm = (const float*)d_in[5];
  float* out = (float*)d_out;

  unsigned short* nn_idx = (unsigned short*)d_ws;   // 1 MB

  knn_kernel<<<dim3(N2 / 16, B), 512, 0, stream>>>(xyz1, xyz2, nn_idx);
  conv_kernel<<<dim3(N2 / 32, B), 512, 0, stream>>>(xyz1, feat1, xyz2, feat2,
                                                    kp, Wm, nn_idx, out);
}

// Round 11
// 793.144 us; speedup vs baseline: 2.0165x; 2.0165x over previous
//
#include <hip/hip_runtime.h>

#define B 4
#define N1 2048
#define N2 8192
#define C1 128
#define C2 64
#define K 15
#define F 128
#define S 16

// ---------------------------------------------------------------------------
// kNN: R9-VERBATIM (validated: absmax 0.03125). 512 threads = 16 queries x
// 32 subchunk lists; strided subscans + 5-round lex-(d,idx) tree merge.
// ---------------------------------------------------------------------------
__global__ __launch_bounds__(512) void knn_kernel(
    const float* __restrict__ xyz1, const float* __restrict__ xyz2,
    unsigned short* __restrict__ nn_idx) {
#pragma clang fp contract(off)
  __shared__ float sx[N1], sy[N1], sz[N1];
  __shared__ float s_cd[16][522];
  __shared__ unsigned short s_ci[16][522];
  const int b = blockIdx.y;
  const int q0 = blockIdx.x * 16;
  const int tid = threadIdx.x;

  const float* p1 = xyz1 + (size_t)b * N1 * 3;
  for (int i = tid; i < N1; i += 512) {
    sx[i] = p1[i * 3 + 0];
    sy[i] = p1[i * 3 + 1];
    sz[i] = p1[i * 3 + 2];
  }
  __syncthreads();

  const int wv = tid >> 6;
  const int lane = tid & 63;
  const int q = lane & 15;
  const int sub = lane >> 4;
  const float* p2 = xyz2 + ((size_t)b * N2 + q0 + q) * 3;
  const float qx = p2[0], qy = p2[1], qz = p2[2];

  float bd[S];
  int bi[S];
#pragma unroll
  for (int j = 0; j < S; ++j) { bd[j] = 3.4e38f; bi[j] = 0x7fffffff; }

  const int i0 = wv * 256 + sub;
  for (int ii = 0; ii < 64; ++ii) {
    const int i = i0 + (ii << 2);
    float dx = qx - sx[i];
    float dy = qy - sy[i];
    float dz = qz - sz[i];
    float d = dx * dx;
    d = d + dy * dy;
    d = d + dz * dz;
    if (d < bd[S - 1]) {
      bd[S - 1] = d;
      bi[S - 1] = i;
#pragma unroll
      for (int j = S - 1; j > 0; --j) {
        if (bd[j] < bd[j - 1]) {
          float td = bd[j]; bd[j] = bd[j - 1]; bd[j - 1] = td;
          int ti = bi[j]; bi[j] = bi[j - 1]; bi[j - 1] = ti;
        }
      }
    }
  }
  {
    const int ls = (wv * 4 + sub) * 16;
#pragma unroll
    for (int j = 0; j < S; ++j) {
      s_cd[q][ls + j] = bd[j];
      s_ci[q][ls + j] = (unsigned short)bi[j];
    }
  }
  __syncthreads();

  for (int L = 32; L >= 4; L >>= 1) {
    const int half = L >> 1;
    const int nact = 16 * half;
    const int valid = tid < nact;
    float od[16];
    int oi[16];
    int q2 = 0, m = 0;
    if (valid) {
      q2 = tid / half;
      m = tid - q2 * half;
      int pa = (2 * m) * 16, ea = pa + 16;
      int pb = ea, eb = pb + 16;
#pragma unroll
      for (int j = 0; j < 16; ++j) {
        const int a_ok = pa < ea, b_ok = pb < eb;
        const int ra = a_ok ? pa : ea - 1;
        const int rb = b_ok ? pb : eb - 1;
        float da = s_cd[q2][ra];
        int ia = (int)s_ci[q2][ra];
        float db = s_cd[q2][rb];
        int ib = (int)s_ci[q2][rb];
        const int ta = a_ok && (!b_ok || da < db || (da == db && ia < ib));
        od[j] = ta ? da : db;
        oi[j] = ta ? ia : ib;
        pa += ta;
        pb += !ta;
      }
    }
    __syncthreads();
    if (valid) {
#pragma unroll
      for (int j = 0; j < 16; ++j) {
        s_cd[q2][m * 16 + j] = od[j];
        s_ci[q2][m * 16 + j] = (unsigned short)oi[j];
      }
    }
    __syncthreads();
  }

  if (tid < 16) {
    const int q2 = tid;
    int pa = 0, ea = 16, pb = 16, eb = 32;
    unsigned short* op = nn_idx + ((size_t)b * N2 + q0 + q2) * S;
#pragma unroll
    for (int j = 0; j < 16; ++j) {
      const int a_ok = pa < ea, b_ok = pb < eb;
      const int ra = a_ok ? pa : ea - 1;
      const int rb = b_ok ? pb : eb - 1;
      float da = s_cd[q2][ra];
      int ia = (int)s_ci[q2][ra];
      float db = s_cd[q2][rb];
      int ib = (int)s_ci[q2][rb];
      const int ta = a_ok && (!b_ok || da < db || (da == db && ia < ib));
      op[j] = (unsigned short)(ta ? ia : ib);
      pa += ta;
      pb += !ta;
    }
  }
}

// ---------------------------------------------------------------------------
// Conv: R10 structure, single change: __launch_bounds__(512, 2) — R10's
// (512,4) capped VGPR at 64 and spilled accumulators to scratch (FETCH_SIZE
// 2.79 GB). Cap ~128 fits the ~110 live regs; occupancy LDS-capped at
// 2 blocks/CU = 16 waves. Accumulation order identical to R8.
// ---------------------------------------------------------------------------
__global__ __launch_bounds__(512, 2) void conv_kernel(
    const float* __restrict__ xyz1, const float* __restrict__ feat1,
    const float* __restrict__ xyz2, const float* __restrict__ feat2,
    const float* __restrict__ kp, const float* __restrict__ W,
    const unsigned short* __restrict__ nn_idx, float* __restrict__ out) {
  __shared__ int s_idx[32][S];          //  2 KB
  __shared__ float s_rel[32][S][3];     //  6 KB
  __shared__ float s_w[32][260];        // 33.3 KB
  __shared__ float s_wf[C1][36];        // 18.4 KB
  __shared__ float s_part[4][8][132];   // 16.9 KB
  __shared__ float s_kp[K * 3];

  const int b = blockIdx.y;
  const int q0 = blockIdx.x * 32;
  const int tid = threadIdx.x;

  if (tid < K * 3) s_kp[tid] = kp[tid];
  s_idx[tid >> 4][tid & 15] = (int)nn_idx[((size_t)b * N2 + q0) * S + tid];
  __syncthreads();

  {
    int q = tid >> 4, s = tid & 15;
    int i = s_idx[q][s];
    const float* pn = xyz1 + ((size_t)b * N1 + i) * 3;
    const float* pq = xyz2 + ((size_t)b * N2 + q0 + q) * 3;
    s_rel[q][s][0] = pn[0] - pq[0];
    s_rel[q][s][1] = pn[1] - pq[1];
    s_rel[q][s][2] = pn[2] - pq[2];
  }
  __syncthreads();

  for (int t = tid; t < 32 * S * K; t += 512) {
    int q = t / (S * K);
    int r = t - q * (S * K);
    int s = r / K;
    int k = r - s * K;
    float rx = s_rel[q][s][0] - s_kp[k * 3 + 0];
    float ry = s_rel[q][s][1] - s_kp[k * 3 + 1];
    float rz = s_rel[q][s][2] - s_kp[k * 3 + 2];
    float d = sqrtf(fmaxf(rx * rx + ry * ry + rz * rz, 1e-12f));
    s_w[q][s * 16 + k] = fmaxf(0.0f, 1.0f - d / 0.2f);
  }
  __syncthreads();

  const int q = tid & 31;        // phase-B query
  const int cg = tid >> 5;       // phase-B c-group
  const int qg = tid >> 7;       // phase-C q-octet
  const int cs = (tid >> 5) & 3; // phase-C c-quarter
  const int fg = tid & 31;       // phase-C f-quad

  float4 acc[8];
#pragma unroll
  for (int qi = 0; qi < 8; ++qi) acc[qi] = make_float4(0.f, 0.f, 0.f, 0.f);

#pragma unroll
  for (int kc = 0; kc < 3; ++kc) {
    float wfr[5][8];
#pragma unroll
    for (int kk = 0; kk < 5; ++kk)
#pragma unroll
      for (int j = 0; j < 8; ++j) wfr[kk][j] = 0.0f;

    for (int s = 0; s < S; ++s) {
      int i = s_idx[q][s];
      const float4* fp =
          (const float4*)(feat1 + ((size_t)b * N1 + i) * C1) + cg * 2;
      float4 n0 = fp[0];
      float4 n1 = fp[1];
      const float4* wr = (const float4*)(&s_w[q][s * 16]);
      float4 w0 = wr[0], w1 = wr[1], w2 = wr[2], w3 = wr[3];
      float wk[16] = {w0.x, w0.y, w0.z, w0.w, w1.x, w1.y, w1.z, w1.w,
                      w2.x, w2.y, w2.z, w2.w, w3.x, w3.y, w3.z, w3.w};
#pragma unroll
      for (int kk = 0; kk < 5; ++kk) {
        float w = wk[kc * 5 + kk];
        wfr[kk][0] += w * n0.x;
        wfr[kk][1] += w * n0.y;
        wfr[kk][2] += w * n0.z;
        wfr[kk][3] += w * n0.w;
        wfr[kk][4] += w * n1.x;
        wfr[kk][5] += w * n1.y;
        wfr[kk][6] += w * n1.z;
        wfr[kk][7] += w * n1.w;
      }
    }

#pragma unroll
    for (int kk = 0; kk < 5; ++kk) {
      const int k = kc * 5 + kk;
      __syncthreads();
#pragma unroll
      for (int j = 0; j < 8; ++j) s_wf[cg * 8 + j][q] = wfr[kk][j];
      __syncthreads();

      const float4* Wk4 = (const float4*)(W + (size_t)k * C1 * F) + fg;
#pragma unroll 4
      for (int c2 = 0; c2 < 32; ++c2) {
        int c = cs * 32 + c2;
        float4 wa = *(const float4*)(&s_wf[c][qg * 8 + 0]);
        float4 wb = *(const float4*)(&s_wf[c][qg * 8 + 4]);
        float4 w4 = Wk4[c * 32];
        acc[0].x += wa.x * w4.x; acc[0].y += wa.x * w4.y;
        acc[0].z += wa.x * w4.z; acc[0].w += wa.x * w4.w;
        acc[1].x += wa.y * w4.x; acc[1].y += wa.y * w4.y;
        acc[1].z += wa.y * w4.z; acc[1].w += wa.y * w4.w;
        acc[2].x += wa.z * w4.x; acc[2].y += wa.z * w4.y;
        acc[2].z += wa.z * w4.z; acc[2].w += wa.z * w4.w;
        acc[3].x += wa.w * w4.x; acc[3].y += wa.w * w4.y;
        acc[3].z += wa.w * w4.z; acc[3].w += wa.w * w4.w;
        acc[4].x += wb.x * w4.x; acc[4].y += wb.x * w4.y;
        acc[4].z += wb.x * w4.z; acc[4].w += wb.x * w4.w;
        acc[5].x += wb.y * w4.x; acc[5].y += wb.y * w4.y;
        acc[5].z += wb.y * w4.z; acc[5].w += wb.y * w4.w;
        acc[6].x += wb.z * w4.x; acc[6].y += wb.z * w4.y;
        acc[6].z += wb.z * w4.z; acc[6].w += wb.z * w4.w;
        acc[7].x += wb.w * w4.x; acc[7].y += wb.w * w4.y;
        acc[7].z += wb.w * w4.z; acc[7].w += wb.w * w4.w;
      }
    }
  }

  // In-wave cs-pair reduce (lanes L, L^32 share qg/fg)
#pragma unroll
  for (int qi = 0; qi < 8; ++qi) {
    acc[qi].x += __shfl_xor(acc[qi].x, 32, 64);
    acc[qi].y += __shfl_xor(acc[qi].y, 32, 64);
    acc[qi].z += __shfl_xor(acc[qi].z, 32, 64);
    acc[qi].w += __shfl_xor(acc[qi].w, 32, 64);
  }

  const int wv = tid >> 6;
  const int lane = tid & 63;
  __syncthreads();
  if ((wv & 1) && lane < 32) {
#pragma unroll
    for (int qi = 0; qi < 8; ++qi)
      *(float4*)(&s_part[qg][qi][fg * 4]) = acc[qi];
  }
  __syncthreads();
  if (!(wv & 1) && lane < 32) {
#pragma unroll
    for (int qi = 0; qi < 8; ++qi) {
      float4 p = *(const float4*)(&s_part[qg][qi][fg * 4]);
      float4 v;
      v.x = fmaxf(acc[qi].x + p.x, 0.0f);
      v.y = fmaxf(acc[qi].y + p.y, 0.0f);
      v.z = fmaxf(acc[qi].z + p.z, 0.0f);
      v.w = fmaxf(acc[qi].w + p.w, 0.0f);
      ((float4*)(out + ((size_t)b * N2 + q0 + qg * 8 + qi) * (F + C2)))[fg] = v;
    }
  }

  {
    int qq = tid >> 4;
    int j = tid & 15;
    float4 v = ((const float4*)(feat2 + ((size_t)b * N2 + q0 + qq) * C2))[j];
    ((float4*)(out + ((size_t)b * N2 + q0 + qq) * (F + C2) + F))[j] = v;
  }
}

extern "C" void kernel_launch(void* const* d_in, const int* in_sizes, int n_in,
                              void* d_out, int out_size, void* d_ws, size_t ws_size,
                              hipStream_t stream) {
  const float* xyz1 = (const float*)d_in[0];
  const float* feat1 = (const float*)d_in[1];
  const float* xyz2 = (const float*)d_in[2];
  const float* feat2 = (const float*)d_in[3];
  const float* kp = (const float*)d_in[4];
  const float* Wm = (const float*)d_in[5];
  float* out = (float*)d_out;

  unsigned short* nn_idx = (unsigned short*)d_ws;   // 1 MB

  knn_kernel<<<dim3(N2 / 16, B), 512, 0, stream>>>(xyz1, xyz2, nn_idx);
  conv_kernel<<<dim3(N2 / 32, B), 512, 0, stream>>>(xyz1, feat1, xyz2, feat2,
                                                    kp, Wm, nn_idx, out);
}